// Round 1
// baseline (219.302 us; speedup 1.0000x reference)
//
#include <hip/hip_runtime.h>

#define POOLSZ 7
#define IMG_H  28
#define IMG_W  28
#define IMG_C  512
#define C4     128            // float4 groups per pixel (512/4)
#define HALF4  64             // float4 groups per channel-half
#define PATCH  6              // 7x7 samples span <4 px -> 6x6 patch suffices
#define NPIX   (PATCH * PATCH)
#define TOT_ROIS 2048         // 16 * 128 from the reshape

typedef float f4 __attribute__((ext_vector_type(4)));

// 4 LDS tap offsets (in f4 units) + 4 bilinear weights (mask folded in)
struct __align__(16) Desc { int o0, o1, o2, o3; float w0, w1, w2, w3; };

__global__ __launch_bounds__(256, 4)
void roi_crop_resize_v2(const float* __restrict__ img,
                        const float* __restrict__ rois,
                        float* __restrict__ out) {
    // 36 pixels * 64 f4 * 16 B = 36864 B patch + 1568 B desc -> 4 blocks/CU
    __shared__ f4   patch[NPIX * HALF4];
    __shared__ Desc desc[49];

    int n    = blockIdx.x >> 1;      // ROI id 0..2047
    int half = blockIdx.x & 1;       // channel half 0..1

    // boxes: x1 = col3, y1 = col4 of flattened (N,5) rois; both in [0,1)
    float x1 = rois[n * 5 + 3];
    float y1 = rois[n * 5 + 4];
    // replicate reference arithmetic order exactly
    float x2 = x1 + 4.0f / 28.0f;
    float y2 = y1 + 4.0f / 28.0f;
    const float Hm1 = 27.0f, Wm1 = 27.0f;
    float dy  = (y2 - y1) * Hm1 / 6.0f;   // ((y2-y1)*27)/6, same assoc as ref
    float dx  = (x2 - x1) * Wm1 / 6.0f;
    float ys0 = y1 * Hm1;                 // >= 0 always (y1 in [0,1))
    float xs0 = x1 * Wm1;

    int Y0 = (int)floorf(ys0); if (Y0 > 27) Y0 = 27; if (Y0 < 0) Y0 = 0;
    int X0 = (int)floorf(xs0); if (X0 > 27) X0 = 27; if (X0 < 0) X0 = 0;

    const f4* img4 = (const f4*)img;   // only img[0] is used
    int tid   = threadIdx.x;
    int cbase = half * HALF4;

    // ---- stage 6x6 patch (rows/cols clamped to 27) for this channel half ----
    // per wave: pix uniform, c = lane -> 1 KB contiguous global load, no LDS conflicts
    for (int i = tid; i < NPIX * HALF4; i += 256) {
        int c   = i & (HALF4 - 1);
        int pix = i >> 6;                       // 0..35
        int ry  = Y0 + pix / PATCH; if (ry > 27) ry = 27;
        int rx  = X0 + pix % PATCH; if (rx > 27) rx = 27;
        patch[i] = img4[(ry * IMG_W + rx) * C4 + cbase + c];
    }

    // ---- precompute the 49 sample descriptors (shared across all channels) ----
    if (tid < 49) {
        int py = tid / POOLSZ, px = tid % POOLSZ;
        float ys = ys0 + (float)py * dy;
        float xs = xs0 + (float)px * dx;
        float y0f = floorf(ys), x0f = floorf(xs);
        float ly = ys - y0f, lx = xs - x0f;
        int y0  = (int)fminf(fmaxf(y0f,       0.f), Hm1);
        int y1i = (int)fminf(fmaxf(y0f + 1.f, 0.f), Hm1);
        int x0  = (int)fminf(fmaxf(x0f,       0.f), Wm1);
        int x1i = (int)fminf(fmaxf(x0f + 1.f, 0.f), Wm1);
        float m = ((ys >= 0.f) & (ys <= Hm1) & (xs >= 0.f) & (xs <= Wm1)) ? 1.f : 0.f;

        // LDS patch indices — provably in [0,5]: window span 6*dy < 4 px,
        // floor(ys)>=Y0 since ys>=ys0>=0, clamps are monotone.
        int ry0 = y0  - Y0, ry1 = y1i - Y0;
        int rx0 = x0  - X0, rx1 = x1i - X0;
        float omlx = 1.f - lx, omly = 1.f - ly;

        Desc d;
        d.o0 = (ry0 * PATCH + rx0) * HALF4;
        d.o1 = (ry0 * PATCH + rx1) * HALF4;
        d.o2 = (ry1 * PATCH + rx0) * HALF4;
        d.o3 = (ry1 * PATCH + rx1) * HALF4;
        d.w0 = omlx * omly * m;
        d.w1 = lx   * omly * m;
        d.w2 = omlx * ly   * m;
        d.w3 = lx   * ly   * m;
        desc[tid] = d;
    }
    __syncthreads();

    // ---- compute 49 positions x 64 f4 from LDS ----
    // per wave: p uniform (desc read = free broadcast), c = lane ->
    // conflict-free ds_read_b128 taps + 1 KB contiguous nontemporal store
    f4* out4 = (f4*)out;
    int outBase = n * 49 * C4 + cbase;
    for (int i = tid; i < 49 * HALF4; i += 256) {
        int c = i & (HALF4 - 1);
        int p = i >> 6;                         // 0..48
        Desc d = desc[p];
        f4 tl = patch[d.o0 + c];
        f4 tr = patch[d.o1 + c];
        f4 bl = patch[d.o2 + c];
        f4 br = patch[d.o3 + c];
        f4 v = tl * d.w0 + tr * d.w1 + bl * d.w2 + br * d.w3;
        __builtin_nontemporal_store(v, out4 + outBase + p * C4 + c);
    }
}

extern "C" void kernel_launch(void* const* d_in, const int* in_sizes, int n_in,
                              void* d_out, int out_size, void* d_ws, size_t ws_size,
                              hipStream_t stream) {
    const float* img  = (const float*)d_in[0];
    const float* rois = (const float*)d_in[1];
    float* out = (float*)d_out;

    // 2048 ROIs x 2 channel halves
    roi_crop_resize_v2<<<TOT_ROIS * 2, 256, 0, stream>>>(img, rois, out);
}

// Round 2
// 212.965 us; speedup vs baseline: 1.0298x; 1.0298x over previous
//
#include <hip/hip_runtime.h>

#define POOLSZ 7
#define IMG_H  28
#define IMG_W  28
#define IMG_C  512
#define C4     128            // float4 groups per pixel (512/4)
#define HALF4  64             // float4 groups per channel-half
#define PATCH  6              // 7x7 samples span <4 px -> 6x6 patch suffices
#define NPIX   (PATCH * PATCH)
#define TOT_ROIS 2048         // 16 * 128 from the reshape

typedef float f4 __attribute__((ext_vector_type(4)));

__global__ __launch_bounds__(256, 4)
void roi_crop_resize_v3(const float* __restrict__ img,
                        const float* __restrict__ rois,
                        float* __restrict__ out) {
    // 36 pixels * 64 f4 * 16 B = 36864 B -> 4 blocks/CU (16 waves)
    __shared__ f4 patch[NPIX * HALF4];

    int n    = blockIdx.x >> 1;      // ROI id 0..2047
    int half = blockIdx.x & 1;       // channel half 0..1

    // boxes: x1 = col3, y1 = col4 of flattened (N,5) rois; both in [0,1)
    float x1 = rois[n * 5 + 3];
    float y1 = rois[n * 5 + 4];
    // replicate reference arithmetic order exactly
    float x2 = x1 + 4.0f / 28.0f;
    float y2 = y1 + 4.0f / 28.0f;
    const float Hm1 = 27.0f, Wm1 = 27.0f;
    float dy  = (y2 - y1) * Hm1 / 6.0f;   // ((y2-y1)*27)/6, same assoc as ref
    float dx  = (x2 - x1) * Wm1 / 6.0f;
    float ys0 = y1 * Hm1;                 // >= 0 always (y1 in [0,1))
    float xs0 = x1 * Wm1;

    int Y0 = (int)floorf(ys0); if (Y0 > 27) Y0 = 27; if (Y0 < 0) Y0 = 0;
    int X0 = (int)floorf(xs0); if (X0 > 27) X0 = 27; if (X0 < 0) X0 = 0;

    const f4* img4 = (const f4*)img;   // only img[0] is used
    int tid   = threadIdx.x;
    int cbase = half * HALF4;

    // ---- stage 6x6 patch (rows/cols clamped to 27) for this channel half ----
    // per wave: pix uniform, c = lane -> 1 KB contiguous global load, no LDS conflicts
    for (int i = tid; i < NPIX * HALF4; i += 256) {
        int c   = i & (HALF4 - 1);
        int pix = i >> 6;                       // 0..35
        int ry  = Y0 + pix / PATCH; if (ry > 27) ry = 27;
        int rx  = X0 + pix % PATCH; if (rx > 27) rx = 27;
        patch[i] = img4[(ry * IMG_W + rx) * C4 + cbase + c];
    }
    __syncthreads();

    // ---- compute 49 positions x 64 f4 from LDS ----
    // p = i>>6 is wave-uniform: sample math computed inline (~30 VALU, cheap),
    // no desc[] table, only 4 LDS b128 reads per item.
    // Stores: PLAIN (not nontemporal) — testing the nt-write-throughput theory.
    f4* out4 = (f4*)out + n * 49 * C4 + cbase;
    for (int i = tid; i < 49 * HALF4; i += 256) {
        int c = i & (HALF4 - 1);
        int p = i >> 6;                         // 0..48, uniform across the wave
        int py = p / POOLSZ, px = p % POOLSZ;

        float ys = ys0 + (float)py * dy;
        float xs = xs0 + (float)px * dx;
        float y0f = floorf(ys), x0f = floorf(xs);
        float ly = ys - y0f, lx = xs - x0f;
        int y0  = (int)fminf(fmaxf(y0f,       0.f), Hm1);
        int y1i = (int)fminf(fmaxf(y0f + 1.f, 0.f), Hm1);
        int x0  = (int)fminf(fmaxf(x0f,       0.f), Wm1);
        int x1i = (int)fminf(fmaxf(x0f + 1.f, 0.f), Wm1);
        float m = ((ys >= 0.f) & (ys <= Hm1) & (xs >= 0.f) & (xs <= Wm1)) ? 1.f : 0.f;

        // LDS patch indices — provably in [0,5]: window span 6*dy < 4 px,
        // floor(ys)>=Y0 since ys>=ys0>=0, clamps are monotone.
        int ry0 = y0  - Y0, ry1 = y1i - Y0;
        int rx0 = x0  - X0, rx1 = x1i - X0;
        f4 tl = patch[(ry0 * PATCH + rx0) * HALF4 + c];
        f4 tr = patch[(ry0 * PATCH + rx1) * HALF4 + c];
        f4 bl = patch[(ry1 * PATCH + rx0) * HALF4 + c];
        f4 br = patch[(ry1 * PATCH + rx1) * HALF4 + c];

        float omly = 1.f - ly;
        f4 v = ((tl + (tr - tl) * lx) * omly + (bl + (br - bl) * lx) * ly) * m;

        out4[p * C4 + c] = v;                   // plain store
    }
}

extern "C" void kernel_launch(void* const* d_in, const int* in_sizes, int n_in,
                              void* d_out, int out_size, void* d_ws, size_t ws_size,
                              hipStream_t stream) {
    const float* img  = (const float*)d_in[0];
    const float* rois = (const float*)d_in[1];
    float* out = (float*)d_out;

    // 2048 ROIs x 2 channel halves
    roi_crop_resize_v3<<<TOT_ROIS * 2, 256, 0, stream>>>(img, rois, out);
}